// Round 2
// baseline (3478.450 us; speedup 1.0000x reference)
//
#include <hip/hip_runtime.h>
#include <math.h>

#define NNODES 5000
#define NEDGES 50000
#define NELG   200000
#define DMODEL 512
#define NH     8
#define NLAYERS 2

typedef __bf16 bf16x8 __attribute__((ext_vector_type(8)));
typedef float  f32x4  __attribute__((ext_vector_type(4)));
typedef unsigned short us8v __attribute__((ext_vector_type(8)));

// ---- bf16 helpers (stored as unsigned short) ------------------------------
__device__ __forceinline__ float b2f(unsigned short u) {
    union { unsigned int i; float f; } c;
    c.i = ((unsigned int)u) << 16;
    return c.f;
}
__device__ __forceinline__ unsigned short f2b(float f) {
    union { float f; unsigned int i; } c;
    c.f = f;
    unsigned int i = c.i;
    return (unsigned short)((i + 0x7fffu + ((i >> 16) & 1u)) >> 16);
}

// ---------------------------------------------------------------------------
// MFMA GEMM with section routing. 3-deep software pipeline with COUNTED
// vmcnt waits and raw s_barrier (loads stay in flight ACROSS barriers —
// the __syncthreads vmcnt(0) drain was the round-0/1 stall). Per iter:
//   STAGE(tile t+2) -> s_waitcnt vmcnt(8) (tile t's 4 loads retired,
//   t+1/t+2 stay in flight) -> s_barrier -> COMPUTE(t) -> s_barrier.
// BK=32, 3 x 16 KB buffers = 48 KB LDS -> 3 blocks/CU (TLP preserved).
// Chunk-XOR swizzle keeps ds_read_b128 conflict-free.
// Grid: x = N-tiles (FAST), y = M-tiles.
// ---------------------------------------------------------------------------
#define BM 128
#define BN 128
#define BK 32
#define NBUF 3

struct GemmDst {
    unsigned short* C0; unsigned short* C1; unsigned short* C2;
    const unsigned short* a0; const unsigned short* a1; const unsigned short* a2;
    const int* x0; const int* x1; const int* x2;
    const float* b0; const float* b1; const float* b2;
};

__global__ __launch_bounds__(256) void mfma_gemm_kernel(
    const unsigned short* __restrict__ A, const unsigned short* __restrict__ Bt,
    GemmDst P, int M, int K, int N, int secN, int relu)
{
    __shared__ __align__(16) unsigned short ldsA[NBUF][BM * BK];  // 3 x 8 KB
    __shared__ __align__(16) unsigned short ldsB[NBUF][BN * BK];  // 3 x 8 KB

    const int rowBase = blockIdx.y * BM;
    const int colBase = blockIdx.x * BN;

    const int tid  = threadIdx.x;
    const int lane = tid & 63;
    const int wave = tid >> 6;
    const int quad = lane >> 4;
    const int l16  = lane & 15;
    const int wm = (wave >> 1) * 64;
    const int wn = (wave & 1) * 64;

    // staging: group g -> LDS slot g (16 B). row=g>>2, slot=g&3.
    // slot s holds global chunk c = s ^ ((row>>1)&3)  (XOR swizzle)
    const int g0 = tid, g1 = tid + 256;
    const int r0 = g0 >> 2, r1 = g1 >> 2;
    const int c0g = (g0 & 3) ^ ((r0 >> 1) & 3);
    const int c1g = (g1 & 3) ^ ((r1 >> 1) & 3);
    int ra0 = rowBase + r0; if (ra0 > M - 1) ra0 = M - 1;
    int ra1 = rowBase + r1; if (ra1 > M - 1) ra1 = M - 1;
    const unsigned short* gA0 = A + (size_t)ra0 * K + c0g * 8;
    const unsigned short* gA1 = A + (size_t)ra1 * K + c1g * 8;
    const unsigned short* gB0 = Bt + (size_t)(colBase + r0) * K + c0g * 8;
    const unsigned short* gB1 = Bt + (size_t)(colBase + r1) * K + c1g * 8;
    const int lo0 = g0 * 8;
    const int lo1 = g1 * 8;

    const int swz = (l16 >> 1) & 3;
    const int ca = (quad ^ swz) * 8;

    const f32x4 zv = {0.f, 0.f, 0.f, 0.f};
    f32x4 acc[4][4];
    #pragma unroll
    for (int i = 0; i < 4; ++i)
        #pragma unroll
        for (int j = 0; j < 4; ++j) acc[i][j] = zv;

#define STAGE(buf, k0)                                                        \
    {                                                                         \
        unsigned short* dA = ldsA[buf];                                       \
        unsigned short* dB = ldsB[buf];                                       \
        __builtin_amdgcn_global_load_lds(                                     \
            (const __attribute__((address_space(1))) void*)(gA0 + (k0)),      \
            (__attribute__((address_space(3))) void*)(dA + lo0), 16, 0, 0);   \
        __builtin_amdgcn_global_load_lds(                                     \
            (const __attribute__((address_space(1))) void*)(gA1 + (k0)),      \
            (__attribute__((address_space(3))) void*)(dA + lo1), 16, 0, 0);   \
        __builtin_amdgcn_global_load_lds(                                     \
            (const __attribute__((address_space(1))) void*)(gB0 + (k0)),      \
            (__attribute__((address_space(3))) void*)(dB + lo0), 16, 0, 0);   \
        __builtin_amdgcn_global_load_lds(                                     \
            (const __attribute__((address_space(1))) void*)(gB1 + (k0)),      \
            (__attribute__((address_space(3))) void*)(dB + lo1), 16, 0, 0);   \
    }

#define COMPUTE(buf)                                                          \
    {                                                                         \
        const unsigned short* bA = ldsA[buf];                                 \
        const unsigned short* bB = ldsB[buf];                                 \
        bf16x8 af[4], bfr[4];                                                 \
        _Pragma("unroll")                                                     \
        for (int i = 0; i < 4; ++i)                                           \
            af[i] = *(const bf16x8*)(bA + (wm + i * 16 + l16) * BK + ca);     \
        _Pragma("unroll")                                                     \
        for (int j = 0; j < 4; ++j)                                           \
            bfr[j] = *(const bf16x8*)(bB + (wn + j * 16 + l16) * BK + ca);    \
        _Pragma("unroll")                                                     \
        for (int i = 0; i < 4; ++i)                                           \
            _Pragma("unroll")                                                 \
            for (int j = 0; j < 4; ++j)                                       \
                acc[i][j] = __builtin_amdgcn_mfma_f32_16x16x32_bf16(          \
                    af[i], bfr[j], acc[i][j], 0, 0, 0);                       \
    }

    const int nt = K / BK;     // >= 16 for all call sites

    // prologue: tiles 0 and 1 in flight (8 outstanding VMEM/wave-slot)
    STAGE(0, 0);
    STAGE(1, BK);

    int cur = 0, stg = 2;
    for (int t = 0; t < nt - 2; ++t) {
        STAGE(stg, (t + 2) * BK);                    // 12 outstanding
        asm volatile("s_waitcnt vmcnt(8)" ::: "memory");  // tile t retired
        __builtin_amdgcn_s_barrier();                // all waves' tile-t done
        COMPUTE(cur);                                // lgkmcnt by compiler
        __builtin_amdgcn_s_barrier();                // buf[cur] free for stage
        cur = (cur == 2) ? 0 : cur + 1;
        stg = (stg == 2) ? 0 : stg + 1;
    }
    // epilogue: tiles nt-2, nt-1 already in flight
    asm volatile("s_waitcnt vmcnt(4)" ::: "memory");
    __builtin_amdgcn_s_barrier();
    COMPUTE(cur);
    cur = (cur == 2) ? 0 : cur + 1;
    asm volatile("s_waitcnt vmcnt(0)" ::: "memory");
    __builtin_amdgcn_s_barrier();
    COMPUTE(cur);

#undef STAGE
#undef COMPUTE

    const int sec   = colBase / secN;
    const int cbase = colBase - sec * secN;
    unsigned short*       Cs = (sec == 0) ? P.C0 : ((sec == 1) ? P.C1 : P.C2);
    const unsigned short* ad = (sec == 0) ? P.a0 : ((sec == 1) ? P.a1 : P.a2);
    const int*            gx = (sec == 0) ? P.x0 : ((sec == 1) ? P.x1 : P.x2);
    const float*          bs = (sec == 0) ? P.b0 : ((sec == 1) ? P.b1 : P.b2);

    #pragma unroll
    for (int i = 0; i < 4; ++i) {
        #pragma unroll
        for (int r = 0; r < 4; ++r) {
            const int row = rowBase + wm + i * 16 + quad * 4 + r;
            if (row >= M) continue;
            const int arow = gx ? gx[row] : row;
            const unsigned short* addr = ad ? ad + (size_t)arow * secN : nullptr;
            unsigned short* crow = Cs + (size_t)row * secN;
            #pragma unroll
            for (int j = 0; j < 4; ++j) {
                const int col = cbase + wn + j * 16 + l16;
                float v = acc[i][j][r];
                if (bs) v += bs[col];
                if (addr) v += b2f(addr[col]);
                if (relu) v = fmaxf(v, 0.0f);
                crow[col] = f2b(v);
            }
        }
    }
}

// ---------------------------------------------------------------------------
// W[K][N] fp32 -> Wt[N][K] bf16
// ---------------------------------------------------------------------------
__global__ __launch_bounds__(256) void transpose_cast_kernel(
    const float* __restrict__ W, unsigned short* __restrict__ Wt, int K, int N)
{
    __shared__ float t[32][33];
    const int n0 = blockIdx.x << 5, k0 = blockIdx.y << 5;
    const int tx = threadIdx.x & 31, ty = threadIdx.x >> 5;
    #pragma unroll
    for (int r = 0; r < 32; r += 8)
        t[ty + r][tx] = W[(size_t)(k0 + ty + r) * N + n0 + tx];
    __syncthreads();
    #pragma unroll
    for (int r = 0; r < 32; r += 8)
        Wt[(size_t)(n0 + ty + r) * K + k0 + tx] = f2b(t[tx][ty + r]);
}

// ---------------------------------------------------------------------------
// LayerNorm in place over bf16 rows of width 512. One wave per row.
// ---------------------------------------------------------------------------
__global__ __launch_bounds__(256) void ln_kernel(
    unsigned short* __restrict__ x, const float* __restrict__ g,
    const float* __restrict__ b, int M)
{
    const int row = blockIdx.x * 4 + (threadIdx.x >> 6);
    if (row >= M) return;
    const int lane = threadIdx.x & 63;
    unsigned short* xr = x + (size_t)row * DMODEL;

    float vals[8];
    float s = 0.f, s2 = 0.f;
    #pragma unroll
    for (int i = 0; i < 8; ++i) {
        const float v = b2f(xr[lane + i * 64]);
        vals[i] = v; s += v; s2 += v * v;
    }
    #pragma unroll
    for (int o = 32; o > 0; o >>= 1) {
        s  += __shfl_down(s, o);
        s2 += __shfl_down(s2, o);
    }
    s  = __shfl(s, 0);
    s2 = __shfl(s2, 0);
    const float m = s * (1.0f / DMODEL);
    const float var = s2 * (1.0f / DMODEL) - m * m;
    const float r = rsqrtf(var + 1e-5f);
    #pragma unroll
    for (int i = 0; i < 8; ++i) {
        const int c = lane + i * 64;
        xr[c] = f2b((vals[i] - m) * r * g[c] + b[c]);
    }
}

// ---------------------------------------------------------------------------
// CSR build: histogram -> single-block scan -> scatter
// ---------------------------------------------------------------------------
__global__ __launch_bounds__(256) void hist_kernel(
    const int* __restrict__ dst, int* __restrict__ cnt, int ne)
{
    const int j = blockIdx.x * 256 + threadIdx.x;
    if (j < ne) atomicAdd(&cnt[dst[j]], 1);
}

__global__ __launch_bounds__(1024) void scan_kernel(
    const int* __restrict__ cnt, int* __restrict__ off,
    int* __restrict__ cur, int n)
{
    __shared__ int part[1024];
    const int t = threadIdx.x;
    const int chunk = (n + 1023) >> 10;
    const int lo = t * chunk;
    int hi = lo + chunk; if (hi > n) hi = n;
    int s = 0;
    for (int i = lo; i < hi; ++i) s += cnt[i];
    part[t] = s;
    __syncthreads();
    #pragma unroll
    for (int o = 1; o < 1024; o <<= 1) {
        int v = (t >= o) ? part[t - o] : 0;
        __syncthreads();
        part[t] += v;
        __syncthreads();
    }
    int base = (t == 0) ? 0 : part[t - 1];
    const int total = part[1023];
    for (int i = lo; i < hi; ++i) {
        const int c = cnt[i];
        off[i] = base; cur[i] = base;
        base += c;
    }
    if (t == 1023) off[n] = total;
}

__global__ __launch_bounds__(256) void scatter_kernel(
    const int* __restrict__ dst, int* __restrict__ cur,
    int* __restrict__ idx, int ne)
{
    const int j = blockIdx.x * 256 + threadIdx.x;
    if (j < ne) {
        const int p = atomicAdd(&cur[dst[j]], 1);
        idx[p] = j;
    }
}

// ---------------------------------------------------------------------------
// Fused CSR attention, wave-parallel over incident edges.
// ---------------------------------------------------------------------------
__global__ __launch_bounds__(256) void attend_kernel(
    unsigned short* __restrict__ q,
    const unsigned short* __restrict__ k,
    const unsigned short* __restrict__ v,
    const unsigned short* __restrict__ efeat,
    const int* __restrict__ src,
    const int* __restrict__ off, const int* __restrict__ idx,
    int nseg)
{
    __shared__ float accS[4][DMODEL];   // 8 KB
    __shared__ float zS[4][NH];

    const int seg = blockIdx.x;
    if (seg >= nseg) return;
    const int t = threadIdx.x;
    const int wave = t >> 6, lane = t & 63;
    const int c8 = lane * 8;
    unsigned short* qrow = q + (size_t)seg * DMODEL;

    const us8v q8 = *(const us8v*)(qrow + c8);
    float qv[8];
    #pragma unroll
    for (int j = 0; j < 8; ++j) qv[j] = b2f(q8[j]);

    float acc[8] = {0.f, 0.f, 0.f, 0.f, 0.f, 0.f, 0.f, 0.f};
    float zsum = 0.f;
    const int lo = off[seg], hi = off[seg + 1];
    for (int jj = lo + wave; jj < hi; jj += 4) {
        const int e = idx[jj];
        const int s = src[e];
        const us8v k8 = *(const us8v*)(k + (size_t)s * DMODEL + c8);
        const us8v v8 = *(const us8v*)(v + (size_t)s * DMODEL + c8);
        float p = 0.f;
        float vv[8];
        if (efeat) {
            const us8v e8 = *(const us8v*)(efeat + (size_t)e * DMODEL + c8);
            #pragma unroll
            for (int j = 0; j < 8; ++j) {
                const float ef = b2f(e8[j]);
                p = fmaf(b2f(k8[j]) + ef, qv[j], p);
                vv[j] = b2f(v8[j]) + ef;
            }
        } else {
            #pragma unroll
            for (int j = 0; j < 8; ++j) {
                p = fmaf(b2f(k8[j]), qv[j], p);
                vv[j] = b2f(v8[j]);
            }
        }
        p += __shfl_xor(p, 1);
        p += __shfl_xor(p, 2);
        p += __shfl_xor(p, 4);
        float sc = p * 0.125f;                    // 1/sqrt(64)
        sc = fminf(fmaxf(sc, -10.0f), 10.0f);
        sc = __expf(sc);
        zsum += sc;
        #pragma unroll
        for (int j = 0; j < 8; ++j) acc[j] = fmaf(sc, vv[j], acc[j]);
    }

    #pragma unroll
    for (int j = 0; j < 8; ++j) accS[wave][c8 + j] = acc[j];
    if ((lane & 7) == 0) zS[wave][lane >> 3] = zsum;
    __syncthreads();

    const int c0 = t * 2;
    const int h = c0 >> 6;
    const float a0 = accS[0][c0] + accS[1][c0] + accS[2][c0] + accS[3][c0];
    const float a1 = accS[0][c0 + 1] + accS[1][c0 + 1] + accS[2][c0 + 1] + accS[3][c0 + 1];
    const float z  = zS[0][h] + zS[1][h] + zS[2][h] + zS[3][h];
    const float rz = 1.0f / z;
    ushort2 o2;
    o2.x = f2b(a0 * rz);
    o2.y = f2b(a1 * rz);
    *(ushort2*)(qrow + c0) = o2;
}

// ---------------------------------------------------------------------------
__global__ __launch_bounds__(256) void gather_rel_kernel(
    const float* __restrict__ rel, const int* __restrict__ ef,
    unsigned short* __restrict__ lg)
{
    const int idx = blockIdx.x * 256 + threadIdx.x;
    if (idx >= NEDGES * DMODEL) return;
    const int e = idx >> 9;
    const int col = idx & 511;
    lg[idx] = f2b(rel[(size_t)ef[e] * DMODEL + col]);
}

__global__ __launch_bounds__(256) void cast_f2b_kernel(
    const float* __restrict__ in, unsigned short* __restrict__ out, int n)
{
    const int idx = blockIdx.x * 256 + threadIdx.x;
    if (idx < n) out[idx] = f2b(in[idx]);
}

__global__ __launch_bounds__(256) void cast_b2f_kernel(
    const unsigned short* __restrict__ in, float* __restrict__ out, int n)
{
    const int idx = blockIdx.x * 256 + threadIdx.x;
    if (idx < n) out[idx] = b2f(in[idx]);
}

__global__ __launch_bounds__(256) void zero_kernel(float4* __restrict__ p, int n4)
{
    const int idx = blockIdx.x * 256 + threadIdx.x;
    if (idx < n4) p[idx] = make_float4(0.f, 0.f, 0.f, 0.f);
}

// ---------------------------------------------------------------------------
static inline dim3 gemm_grid(int M, int N)
{
    return dim3(N / BN, (M + BM - 1) / BM);   // N-tiles FAST
}

static inline void mgemm(hipStream_t st, const unsigned short* A, const unsigned short* Bt,
                         const float* bias, const unsigned short* add, const int* gidx,
                         unsigned short* C, int M, int K, int N, int relu)
{
    GemmDst P = {C, nullptr, nullptr, add, nullptr, nullptr,
                 gidx, nullptr, nullptr, bias, nullptr, nullptr};
    mfma_gemm_kernel<<<gemm_grid(M, N), 256, 0, st>>>(A, Bt, P, M, K, N, N, relu);
}

static inline void mgemm_qkv(hipStream_t st, const unsigned short* A, const unsigned short* Bt,
                             const float* biasQ,
                             const unsigned short* addQ, const int* gxQ,
                             const unsigned short* addKV, const int* gxKV,
                             unsigned short* Cq, unsigned short* Ck, unsigned short* Cv,
                             int M, int K)
{
    GemmDst P = {Cq, Ck, Cv, addQ, addKV, addKV,
                 gxQ, gxKV, gxKV, biasQ, nullptr, nullptr};
    mfma_gemm_kernel<<<gemm_grid(M, 1536), 256, 0, st>>>(A, Bt, P, M, K, 1536, 512, 0);
}

static inline void tcast(hipStream_t st, const float* W, unsigned short* Wt, int K, int N)
{
    dim3 g(N / 32, K / 32);
    transpose_cast_kernel<<<g, 256, 0, st>>>(W, Wt, K, N);
}
static inline void zero(hipStream_t st, void* p, size_t nfloats)
{
    const int n4 = (int)(nfloats / 4);
    zero_kernel<<<(n4 + 255) / 256, 256, 0, st>>>((float4*)p, n4);
}

extern "C" void kernel_launch(void* const* d_in, const int* in_sizes, int n_in,
                              void* d_out, int out_size, void* d_ws, size_t ws_size,
                              hipStream_t stream)
{
    const float* x_in      = (const float*)d_in[0];
    const int*   edge_feat = (const int*)d_in[1];
    const int*   src_ids   = (const int*)d_in[2];
    const int*   dst_ids   = (const int*)d_in[3];
    const int*   lg_src    = (const int*)d_in[4];
    const int*   lg_dst    = (const int*)d_in[5];
    const float* rel_embed = (const float*)d_in[6];

    const float* n_Wq = (const float*)d_in[7];   const float* n_bq = (const float*)d_in[8];
    const float* n_Wk = (const float*)d_in[9];   const float* n_Wv = (const float*)d_in[10];
    const float* n_Wo = (const float*)d_in[11];  const float* n_bo = (const float*)d_in[12];
    const float* n_lg = (const float*)d_in[13];  const float* n_lb = (const float*)d_in[14];
    const float* n_f1 = (const float*)d_in[15];  const float* n_fb1 = (const float*)d_in[16];
    const float* n_f2 = (const float*)d_in[17];  const float* n_fb2 = (const float*)d_in[18];
    const float* n_fg = (const float*)d_in[19];  const float* n_fb = (const float*)d_in[20];

    const float* e_Wq = (const float*)d_in[21];  const float* e_bq = (const float*)d_in[22];
    const float* e_Wk = (const float*)d_in[23];  const float* e_Wv = (const float*)d_in[24];
    const float* e_Wo = (const float*)d_in[25];  const float* e_bo = (const float*)d_in[26];
    const float* e_lg = (const float*)d_in[27];  const float* e_lb = (const float*)d_in[28];
    const float* e_f1 = (const float*)d_in[29];  const float* e_fb1 = (const float*)d_in[30];
    const float* e_f2 = (const float*)d_in[31];  const float* e_fb2 = (const float*)d_in[32];
    const float* e_fg = (const float*)d_in[33];  const float* e_fb = (const float*)d_in[34];

    const int XSZ  = NNODES * DMODEL;
    const int LGSZ = NEDGES * DMODEL;

    // ---- workspace layout ---------------------------------------------------
    char* ws = (char*)d_ws;
    unsigned short* lg16  = (unsigned short*)(ws);               // 51,200,000 B
    unsigned short* ve16  = (unsigned short*)(ws + 51200000);    // 51,200,000 B
    int* n_off = (int*)(ws + 102400000);
    int* n_cur = (int*)(ws + 102420480);
    int* n_idx = (int*)(ws + 102440960);
    int* e_off = (int*)(ws + 102641664);
    int* e_cur = (int*)(ws + 102842368);
    int* e_idx = (int*)(ws + 103043072);                         // ends 103.84 MB
    unsigned short* xbufA = (unsigned short*)(ws + 110400000);   // 5,120,000 B
    unsigned short* xbufB = (unsigned short*)(ws + 115520000);   // 5,120,000 B

    // ---- d_out scratch (112.64 MB) -----------------------------------------
    char* ob = (char*)d_out;
    unsigned short* qe16 = (unsigned short*)(ob);                // 51.2 MB
    unsigned short* ke16 = (unsigned short*)(ob + 51200000);     // 51.2 MB
    unsigned short* nq16 = (unsigned short*)(ob);
    unsigned short* nk16 = (unsigned short*)(ob + 5120000);
    unsigned short* nv16 = (unsigned short*)(ob + 10240000);
    unsigned short* nhid = (unsigned short*)(ob);                // 20.48 MB
    unsigned short* wtq  = (unsigned short*)(ob + 102400000);    // q|k|v contiguous
    unsigned short* wtk  = (unsigned short*)(ob + 102924288);
    unsigned short* wtv  = (unsigned short*)(ob + 103448576);
    unsigned short* wto  = (unsigned short*)(ob + 103972864);
    unsigned short* wtf1 = (unsigned short*)(ob + 104497152);    // 2 MB
    unsigned short* wtf2 = (unsigned short*)(ob + 106594304);    // 2 MB (ends 108.7 MB)

    // ---- init + CSR build ---------------------------------------------------
    cast_f2b_kernel<<<(XSZ + 255) / 256, 256, 0, stream>>>(x_in, xbufA, XSZ);
    gather_rel_kernel<<<(LGSZ + 255) / 256, 256, 0, stream>>>(rel_embed, edge_feat, lg16);

    zero(stream, n_cur, NNODES);
    zero(stream, e_cur, NEDGES);
    hist_kernel<<<(NEDGES + 255) / 256, 256, 0, stream>>>(dst_ids, n_cur, NEDGES);
    hist_kernel<<<(NELG + 255) / 256, 256, 0, stream>>>(lg_dst, e_cur, NELG);
    scan_kernel<<<1, 1024, 0, stream>>>(n_cur, n_off, n_cur, NNODES);
    scan_kernel<<<1, 1024, 0, stream>>>(e_cur, e_off, e_cur, NEDGES);
    scatter_kernel<<<(NEDGES + 255) / 256, 256, 0, stream>>>(dst_ids, n_cur, n_idx, NEDGES);
    scatter_kernel<<<(NELG + 255) / 256, 256, 0, stream>>>(lg_dst, e_cur, e_idx, NELG);

    unsigned short* xc = xbufA;
    unsigned short* xn = xbufB;

    for (int i = 0; i < NLAYERS; ++i) {
        const size_t wo  = (size_t)i * DMODEL * DMODEL;
        const size_t bo_ = (size_t)i * DMODEL;
        const size_t f1o = (size_t)i * DMODEL * 4 * DMODEL;
        const size_t b1o = (size_t)i * 4 * DMODEL;
        const size_t f2o = (size_t)i * 4 * DMODEL * DMODEL;

        // ================= node update (reads xc, lg16) =================
        tcast(stream, n_Wq + wo, wtq, 512, 512);
        tcast(stream, n_Wk + wo, wtk, 512, 512);
        tcast(stream, n_Wv + wo, wtv, 512, 512);
        tcast(stream, n_Wo + wo, wto, 512, 512);
        tcast(stream, n_f1 + f1o, wtf1, 512, 2048);
        tcast(stream, n_f2 + f2o, wtf2, 2048, 512);

        mgemm_qkv(stream, xc, wtq, n_bq + bo_,
                  nullptr, nullptr, nullptr, nullptr,
                  nq16, nk16, nv16, NNODES, 512);

        attend_kernel<<<NNODES, 256, 0, stream>>>(
            nq16, nk16, nv16, lg16, src_ids, n_off, n_idx, NNODES);

        mgemm(stream, nq16, wto, n_bo + bo_, xc, nullptr, xn, NNODES, 512, 512, 0);
        ln_kernel<<<(NNODES + 3) / 4, 256, 0, stream>>>(xn, n_lg + bo_, n_lb + bo_, NNODES);
        mgemm(stream, xn, wtf1, n_fb1 + b1o, nullptr, nullptr, nhid, NNODES, 512, 2048, 1);
        mgemm(stream, nhid, wtf2, n_fb2 + bo_, xn, nullptr, xn, NNODES, 2048, 512, 0);
        ln_kernel<<<(NNODES + 3) / 4, 256, 0, stream>>>(xn, n_fg + bo_, n_fb + bo_, NNODES);

        // ================= edge update (reads PRE-update xc) =================
        tcast(stream, e_Wq + wo, wtq, 512, 512);
        tcast(stream, e_Wk + wo, wtk, 512, 512);
        tcast(stream, e_Wv + wo, wtv, 512, 512);
        tcast(stream, e_Wo + wo, wto, 512, 512);

        mgemm_qkv(stream, lg16, wtq, e_bq + bo_,
                  xc, dst_ids, xc, src_ids,
                  qe16, ke16, ve16, NEDGES, 512);

        attend_kernel<<<NEDGES, 256, 0, stream>>>(
            qe16, ke16, ve16, nullptr, lg_src, e_off, e_idx, NEDGES);

        mgemm(stream, qe16, wto, e_bo + bo_, lg16, nullptr, lg16, NEDGES, 512, 512, 0);
        ln_kernel<<<(NEDGES + 3) / 4, 256, 0, stream>>>(lg16, e_lg + bo_, e_lb + bo_, NEDGES);

        tcast(stream, e_f1 + f1o, wtf1, 512, 2048);
        tcast(stream, e_f2 + f2o, wtf2, 2048, 512);
        for (int c = 0; c < 4; ++c) {
            unsigned short* y1c = lg16 + (size_t)c * 12500 * DMODEL;
            mgemm(stream, y1c, wtf1, e_fb1 + b1o, nullptr, nullptr, ve16, 12500, 512, 2048, 1);
            mgemm(stream, ve16, wtf2, e_fb2 + bo_, y1c, nullptr, y1c, 12500, 2048, 512, 0);
        }
        ln_kernel<<<(NEDGES + 3) / 4, 256, 0, stream>>>(lg16, e_fg + bo_, e_fb + bo_, NEDGES);

        unsigned short* t = xc; xc = xn; xn = t;
    }

    // final: bf16 -> fp32 d_out (all d_out scratch dead now)
    float* out_f = (float*)d_out;
    cast_b2f_kernel<<<(XSZ + 255) / 256, 256, 0, stream>>>(xc, out_f, XSZ);
    cast_b2f_kernel<<<(LGSZ + 255) / 256, 256, 0, stream>>>(lg16, out_f + XSZ, LGSZ);
}

// Round 3
// 2329.103 us; speedup vs baseline: 1.4935x; 1.4935x over previous
//
#include <hip/hip_runtime.h>
#include <math.h>

#define NNODES 5000
#define NEDGES 50000
#define NELG   200000
#define DMODEL 512
#define NH     8
#define NLAYERS 2

typedef __bf16 bf16x8 __attribute__((ext_vector_type(8)));
typedef float  f32x4  __attribute__((ext_vector_type(4)));
typedef unsigned short us8v __attribute__((ext_vector_type(8)));
typedef unsigned short us4v __attribute__((ext_vector_type(4)));

// ---- bf16 helpers (stored as unsigned short) ------------------------------
__device__ __forceinline__ float b2f(unsigned short u) {
    union { unsigned int i; float f; } c;
    c.i = ((unsigned int)u) << 16;
    return c.f;
}
__device__ __forceinline__ unsigned short f2b(float f) {
    union { float f; unsigned int i; } c;
    c.f = f;
    unsigned int i = c.i;
    return (unsigned short)((i + 0x7fffu + ((i >> 16) & 1u)) >> 16);
}

// ---------------------------------------------------------------------------
// MFMA GEMM with section routing. Round-0 K-loop (BK=32, 16 KB LDS,
// __syncthreads, chunk-XOR swizzle — 8 blocks/CU, TLP does the latency
// hiding). Two new levers:
//  1. Panel-to-XCD swizzle (bijective, m204): all N-tile blocks of one
//     M-panel land on ONE XCD -> A-panel fetched from HBM once, staged
//     loads become L2 hits -> the per-step vmcnt(0) drain shrinks.
//  2. Swapped-operand MFMA (mfma(b,a)): D transposes so each thread owns
//     4 CONSECUTIVE columns of one row -> ushort4 stores/residual loads,
//     float4 bias loads hoisted (epilogue was 64 scalar 2B stores+loads).
// ---------------------------------------------------------------------------
#define BM 128
#define BN 128
#define BK 32

struct GemmDst {
    unsigned short* C0; unsigned short* C1; unsigned short* C2;
    const unsigned short* a0; const unsigned short* a1; const unsigned short* a2;
    const int* x0; const int* x1; const int* x2;
    const float* b0; const float* b1; const float* b2;
};

__global__ __launch_bounds__(256) void mfma_gemm_kernel(
    const unsigned short* __restrict__ A, const unsigned short* __restrict__ Bt,
    GemmDst P, int M, int K, int N, int secN, int relu)
{
    __shared__ __align__(16) unsigned short ldsA[BM * BK];  // 8 KB
    __shared__ __align__(16) unsigned short ldsB[BN * BK];  // 8 KB

    // ---- panel-to-XCD swizzle (bijective remap, dispatch wgid%8 = XCD) ----
    const int nbx  = gridDim.x;                    // N-tiles (fast)
    const int nb   = nbx * gridDim.y;
    const int wgid = blockIdx.y * nbx + blockIdx.x;
    const int xcd  = wgid & 7;
    const int ii   = wgid >> 3;
    const int q8   = nb >> 3, r8 = nb & 7;
    const int base = (xcd < r8) ? xcd * (q8 + 1) : r8 * (q8 + 1) + (xcd - r8) * q8;
    const int tl   = base + ii;                    // contiguous range per XCD
    const int rowBase = (tl / nbx) * BM;
    const int colBase = (tl % nbx) * BN;

    const int tid  = threadIdx.x;
    const int lane = tid & 63;
    const int wave = tid >> 6;
    const int quad = lane >> 4;
    const int l16  = lane & 15;
    const int wm = (wave >> 1) * 64;
    const int wn = (wave & 1) * 64;

    // staging: group g -> LDS slot g (16 B). row=g>>2, slot=g&3.
    // slot s holds global chunk c = s ^ ((row>>1)&3)  (XOR swizzle)
    const int g0 = tid, g1 = tid + 256;
    const int r0 = g0 >> 2, r1 = g1 >> 2;
    const int c0g = (g0 & 3) ^ ((r0 >> 1) & 3);
    const int c1g = (g1 & 3) ^ ((r1 >> 1) & 3);
    int ra0 = rowBase + r0; if (ra0 > M - 1) ra0 = M - 1;
    int ra1 = rowBase + r1; if (ra1 > M - 1) ra1 = M - 1;
    const unsigned short* gA0 = A + (size_t)ra0 * K + c0g * 8;
    const unsigned short* gA1 = A + (size_t)ra1 * K + c1g * 8;
    const unsigned short* gB0 = Bt + (size_t)(colBase + r0) * K + c0g * 8;
    const unsigned short* gB1 = Bt + (size_t)(colBase + r1) * K + c1g * 8;
    unsigned short* lA0 = ldsA + g0 * 8;
    unsigned short* lA1 = ldsA + g1 * 8;
    unsigned short* lB0 = ldsB + g0 * 8;
    unsigned short* lB1 = ldsB + g1 * 8;

    const int swz = (l16 >> 1) & 3;
    const int ca = (quad ^ swz) * 8;

    const f32x4 zv = {0.f, 0.f, 0.f, 0.f};
    f32x4 acc[4][4];
    #pragma unroll
    for (int i = 0; i < 4; ++i)
        #pragma unroll
        for (int j = 0; j < 4; ++j) acc[i][j] = zv;

    for (int k0 = 0; k0 < K; k0 += BK) {
        __builtin_amdgcn_global_load_lds(
            (const __attribute__((address_space(1))) void*)(gA0 + k0),
            (__attribute__((address_space(3))) void*)lA0, 16, 0, 0);
        __builtin_amdgcn_global_load_lds(
            (const __attribute__((address_space(1))) void*)(gA1 + k0),
            (__attribute__((address_space(3))) void*)lA1, 16, 0, 0);
        __builtin_amdgcn_global_load_lds(
            (const __attribute__((address_space(1))) void*)(gB0 + k0),
            (__attribute__((address_space(3))) void*)lB0, 16, 0, 0);
        __builtin_amdgcn_global_load_lds(
            (const __attribute__((address_space(1))) void*)(gB1 + k0),
            (__attribute__((address_space(3))) void*)lB1, 16, 0, 0);
        __syncthreads();

        bf16x8 af[4], bfr[4];
        #pragma unroll
        for (int i = 0; i < 4; ++i)
            af[i] = *(const bf16x8*)(ldsA + (wm + i * 16 + l16) * BK + ca);
        #pragma unroll
        for (int j = 0; j < 4; ++j)
            bfr[j] = *(const bf16x8*)(ldsB + (wn + j * 16 + l16) * BK + ca);
        // swapped operands: D^T layout -> thread owns row m = ...+l16,
        // 4 consecutive cols n = ...+quad*4+r  (vectorizable epilogue)
        #pragma unroll
        for (int i = 0; i < 4; ++i)
            #pragma unroll
            for (int j = 0; j < 4; ++j)
                acc[i][j] = __builtin_amdgcn_mfma_f32_16x16x32_bf16(
                    bfr[j], af[i], acc[i][j], 0, 0, 0);
        __syncthreads();
    }

    const int sec   = colBase / secN;
    const int cbase = colBase - sec * secN;
    unsigned short*       Cs = (sec == 0) ? P.C0 : ((sec == 1) ? P.C1 : P.C2);
    const unsigned short* ad = (sec == 0) ? P.a0 : ((sec == 1) ? P.a1 : P.a2);
    const int*            gx = (sec == 0) ? P.x0 : ((sec == 1) ? P.x1 : P.x2);
    const float*          bs = (sec == 0) ? P.b0 : ((sec == 1) ? P.b1 : P.b2);

    // bias is row-independent: hoist the 4 float4 loads
    f32x4 b4[4];
    #pragma unroll
    for (int j = 0; j < 4; ++j) {
        const int n0 = cbase + wn + j * 16 + quad * 4;
        b4[j] = bs ? *(const f32x4*)(bs + n0) : zv;
    }

    #pragma unroll
    for (int i = 0; i < 4; ++i) {
        const int row = rowBase + wm + i * 16 + l16;
        if (row >= M) continue;
        const int arow = gx ? gx[row] : row;
        const unsigned short* ar = ad ? ad + (size_t)arow * secN : nullptr;
        unsigned short* crow = Cs + (size_t)row * secN;
        #pragma unroll
        for (int j = 0; j < 4; ++j) {
            const int n0 = cbase + wn + j * 16 + quad * 4;
            f32x4 v = acc[i][j];
            v += b4[j];
            if (ar) {
                const us4v r4 = *(const us4v*)(ar + n0);
                #pragma unroll
                for (int r = 0; r < 4; ++r) v[r] += b2f(r4[r]);
            }
            if (relu) {
                #pragma unroll
                for (int r = 0; r < 4; ++r) v[r] = fmaxf(v[r], 0.0f);
            }
            us4v o4;
            #pragma unroll
            for (int r = 0; r < 4; ++r) o4[r] = f2b(v[r]);
            *(us4v*)(crow + n0) = o4;
        }
    }
}

// ---------------------------------------------------------------------------
// W[K][N] fp32 -> Wt[N][K] bf16
// ---------------------------------------------------------------------------
__global__ __launch_bounds__(256) void transpose_cast_kernel(
    const float* __restrict__ W, unsigned short* __restrict__ Wt, int K, int N)
{
    __shared__ float t[32][33];
    const int n0 = blockIdx.x << 5, k0 = blockIdx.y << 5;
    const int tx = threadIdx.x & 31, ty = threadIdx.x >> 5;
    #pragma unroll
    for (int r = 0; r < 32; r += 8)
        t[ty + r][tx] = W[(size_t)(k0 + ty + r) * N + n0 + tx];
    __syncthreads();
    #pragma unroll
    for (int r = 0; r < 32; r += 8)
        Wt[(size_t)(n0 + ty + r) * K + k0 + tx] = f2b(t[tx][ty + r]);
}

// ---------------------------------------------------------------------------
// LayerNorm in place over bf16 rows of width 512. One wave per row.
// ---------------------------------------------------------------------------
__global__ __launch_bounds__(256) void ln_kernel(
    unsigned short* __restrict__ x, const float* __restrict__ g,
    const float* __restrict__ b, int M)
{
    const int row = blockIdx.x * 4 + (threadIdx.x >> 6);
    if (row >= M) return;
    const int lane = threadIdx.x & 63;
    unsigned short* xr = x + (size_t)row * DMODEL;

    float vals[8];
    float s = 0.f, s2 = 0.f;
    #pragma unroll
    for (int i = 0; i < 8; ++i) {
        const float v = b2f(xr[lane + i * 64]);
        vals[i] = v; s += v; s2 += v * v;
    }
    #pragma unroll
    for (int o = 32; o > 0; o >>= 1) {
        s  += __shfl_down(s, o);
        s2 += __shfl_down(s2, o);
    }
    s  = __shfl(s, 0);
    s2 = __shfl(s2, 0);
    const float m = s * (1.0f / DMODEL);
    const float var = s2 * (1.0f / DMODEL) - m * m;
    const float r = rsqrtf(var + 1e-5f);
    #pragma unroll
    for (int i = 0; i < 8; ++i) {
        const int c = lane + i * 64;
        xr[c] = f2b((vals[i] - m) * r * g[c] + b[c]);
    }
}

// ---------------------------------------------------------------------------
// CSR build: histogram -> single-block scan -> scatter
// ---------------------------------------------------------------------------
__global__ __launch_bounds__(256) void hist_kernel(
    const int* __restrict__ dst, int* __restrict__ cnt, int ne)
{
    const int j = blockIdx.x * 256 + threadIdx.x;
    if (j < ne) atomicAdd(&cnt[dst[j]], 1);
}

__global__ __launch_bounds__(1024) void scan_kernel(
    const int* __restrict__ cnt, int* __restrict__ off,
    int* __restrict__ cur, int n)
{
    __shared__ int part[1024];
    const int t = threadIdx.x;
    const int chunk = (n + 1023) >> 10;
    const int lo = t * chunk;
    int hi = lo + chunk; if (hi > n) hi = n;
    int s = 0;
    for (int i = lo; i < hi; ++i) s += cnt[i];
    part[t] = s;
    __syncthreads();
    #pragma unroll
    for (int o = 1; o < 1024; o <<= 1) {
        int v = (t >= o) ? part[t - o] : 0;
        __syncthreads();
        part[t] += v;
        __syncthreads();
    }
    int base = (t == 0) ? 0 : part[t - 1];
    const int total = part[1023];
    for (int i = lo; i < hi; ++i) {
        const int c = cnt[i];
        off[i] = base; cur[i] = base;
        base += c;
    }
    if (t == 1023) off[n] = total;
}

__global__ __launch_bounds__(256) void scatter_kernel(
    const int* __restrict__ dst, int* __restrict__ cur,
    int* __restrict__ idx, int ne)
{
    const int j = blockIdx.x * 256 + threadIdx.x;
    if (j < ne) {
        const int p = atomicAdd(&cur[dst[j]], 1);
        idx[p] = j;
    }
}

// ---------------------------------------------------------------------------
// Fused CSR attention, wave-parallel over incident edges.
// ---------------------------------------------------------------------------
__global__ __launch_bounds__(256) void attend_kernel(
    unsigned short* __restrict__ q,
    const unsigned short* __restrict__ k,
    const unsigned short* __restrict__ v,
    const unsigned short* __restrict__ efeat,
    const int* __restrict__ src,
    const int* __restrict__ off, const int* __restrict__ idx,
    int nseg)
{
    __shared__ float accS[4][DMODEL];   // 8 KB
    __shared__ float zS[4][NH];

    const int seg = blockIdx.x;
    if (seg >= nseg) return;
    const int t = threadIdx.x;
    const int wave = t >> 6, lane = t & 63;
    const int c8 = lane * 8;
    unsigned short* qrow = q + (size_t)seg * DMODEL;

    const us8v q8 = *(const us8v*)(qrow + c8);
    float qv[8];
    #pragma unroll
    for (int j = 0; j < 8; ++j) qv[j] = b2f(q8[j]);

    float acc[8] = {0.f, 0.f, 0.f, 0.f, 0.f, 0.f, 0.f, 0.f};
    float zsum = 0.f;
    const int lo = off[seg], hi = off[seg + 1];
    for (int jj = lo + wave; jj < hi; jj += 4) {
        const int e = idx[jj];
        const int s = src[e];
        const us8v k8 = *(const us8v*)(k + (size_t)s * DMODEL + c8);
        const us8v v8 = *(const us8v*)(v + (size_t)s * DMODEL + c8);
        float p = 0.f;
        float vv[8];
        if (efeat) {
            const us8v e8 = *(const us8v*)(efeat + (size_t)e * DMODEL + c8);
            #pragma unroll
            for (int j = 0; j < 8; ++j) {
                const float ef = b2f(e8[j]);
                p = fmaf(b2f(k8[j]) + ef, qv[j], p);
                vv[j] = b2f(v8[j]) + ef;
            }
        } else {
            #pragma unroll
            for (int j = 0; j < 8; ++j) {
                p = fmaf(b2f(k8[j]), qv[j], p);
                vv[j] = b2f(v8[j]);
            }
        }
        p += __shfl_xor(p, 1);
        p += __shfl_xor(p, 2);
        p += __shfl_xor(p, 4);
        float sc = p * 0.125f;                    // 1/sqrt(64)
        sc = fminf(fmaxf(sc, -10.0f), 10.0f);
        sc = __expf(sc);
        zsum += sc;
        #pragma unroll
        for (int j = 0; j < 8; ++j) acc[j] = fmaf(sc, vv[j], acc[j]);
    }

    #pragma unroll
    for (int j = 0; j < 8; ++j) accS[wave][c8 + j] = acc[j];
    if ((lane & 7) == 0) zS[wave][lane >> 3] = zsum;
    __syncthreads();

    const int c0 = t * 2;
    const int h = c0 >> 6;
    const float a0 = accS[0][c0] + accS[1][c0] + accS[2][c0] + accS[3][c0];
    const float a1 = accS[0][c0 + 1] + accS[1][c0 + 1] + accS[2][c0 + 1] + accS[3][c0 + 1];
    const float z  = zS[0][h] + zS[1][h] + zS[2][h] + zS[3][h];
    const float rz = 1.0f / z;
    ushort2 o2;
    o2.x = f2b(a0 * rz);
    o2.y = f2b(a1 * rz);
    *(ushort2*)(qrow + c0) = o2;
}

// ---------------------------------------------------------------------------
__global__ __launch_bounds__(256) void gather_rel_kernel(
    const float* __restrict__ rel, const int* __restrict__ ef,
    unsigned short* __restrict__ lg)
{
    const int idx = blockIdx.x * 256 + threadIdx.x;
    if (idx >= NEDGES * DMODEL) return;
    const int e = idx >> 9;
    const int col = idx & 511;
    lg[idx] = f2b(rel[(size_t)ef[e] * DMODEL + col]);
}

__global__ __launch_bounds__(256) void cast_f2b_kernel(
    const float* __restrict__ in, unsigned short* __restrict__ out, int n)
{
    const int idx = blockIdx.x * 256 + threadIdx.x;
    if (idx < n) out[idx] = f2b(in[idx]);
}

__global__ __launch_bounds__(256) void cast_b2f_kernel(
    const unsigned short* __restrict__ in, float* __restrict__ out, int n)
{
    const int idx = blockIdx.x * 256 + threadIdx.x;
    if (idx < n) out[idx] = b2f(in[idx]);
}

__global__ __launch_bounds__(256) void zero_kernel(float4* __restrict__ p, int n4)
{
    const int idx = blockIdx.x * 256 + threadIdx.x;
    if (idx < n4) p[idx] = make_float4(0.f, 0.f, 0.f, 0.f);
}

// ---------------------------------------------------------------------------
static inline dim3 gemm_grid(int M, int N)
{
    return dim3(N / BN, (M + BM - 1) / BM);   // N-tiles FAST
}

static inline void mgemm(hipStream_t st, const unsigned short* A, const unsigned short* Bt,
                         const float* bias, const unsigned short* add, const int* gidx,
                         unsigned short* C, int M, int K, int N, int relu)
{
    GemmDst P = {C, nullptr, nullptr, add, nullptr, nullptr,
                 gidx, nullptr, nullptr, bias, nullptr, nullptr};
    mfma_gemm_kernel<<<gemm_grid(M, N), 256, 0, st>>>(A, Bt, P, M, K, N, N, relu);
}

static inline void mgemm_qkv(hipStream_t st, const unsigned short* A, const unsigned short* Bt,
                             const float* biasQ,
                             const unsigned short* addQ, const int* gxQ,
                             const unsigned short* addKV, const int* gxKV,
                             unsigned short* Cq, unsigned short* Ck, unsigned short* Cv,
                             int M, int K)
{
    GemmDst P = {Cq, Ck, Cv, addQ, addKV, addKV,
                 gxQ, gxKV, gxKV, biasQ, nullptr, nullptr};
    mfma_gemm_kernel<<<gemm_grid(M, 1536), 256, 0, st>>>(A, Bt, P, M, K, 1536, 512, 0);
}

static inline void tcast(hipStream_t st, const float* W, unsigned short* Wt, int K, int N)
{
    dim3 g(N / 32, K / 32);
    transpose_cast_kernel<<<g, 256, 0, st>>>(W, Wt, K, N);
}
static inline void zero(hipStream_t st, void* p, size_t nfloats)
{
    const int n4 = (int)(nfloats / 4);
    zero_kernel<<<(n4 + 255) / 256, 256, 0, st>>>((float4*)p, n4);
}

extern "C" void kernel_launch(void* const* d_in, const int* in_sizes, int n_in,
                              void* d_out, int out_size, void* d_ws, size_t ws_size,
                              hipStream_t stream)
{
    const float* x_in      = (const float*)d_in[0];
    const int*   edge_feat = (const int*)d_in[1];
    const int*   src_ids   = (const int*)d_in[2];
    const int*   dst_ids   = (const int*)d_in[3];
    const int*   lg_src    = (const int*)d_in[4];
    const int*   lg_dst    = (const int*)d_in[5];
    const float* rel_embed = (const float*)d_in[6];

    const float* n_Wq = (const float*)d_in[7];   const float* n_bq = (const float*)d_in[8];
    const float* n_Wk = (const float*)d_in[9];   const float* n_Wv = (const float*)d_in[10];
    const float* n_Wo = (const float*)d_in[11];  const float* n_bo = (const float*)d_in[12];
    const float* n_lg = (const float*)d_in[13];  const float* n_lb = (const float*)d_in[14];
    const float* n_f1 = (const float*)d_in[15];  const float* n_fb1 = (const float*)d_in[16];
    const float* n_f2 = (const float*)d_in[17];  const float* n_fb2 = (const float*)d_in[18];
    const float* n_fg = (const float*)d_in[19];  const float* n_fb = (const float*)d_in[20];

    const float* e_Wq = (const float*)d_in[21];  const float* e_bq = (const float*)d_in[22];
    const float* e_Wk = (const float*)d_in[23];  const float* e_Wv = (const float*)d_in[24];
    const float* e_Wo = (const float*)d_in[25];  const float* e_bo = (const float*)d_in[26];
    const float* e_lg = (const float*)d_in[27];  const float* e_lb = (const float*)d_in[28];
    const float* e_f1 = (const float*)d_in[29];  const float* e_fb1 = (const float*)d_in[30];
    const float* e_f2 = (const float*)d_in[31];  const float* e_fb2 = (const float*)d_in[32];
    const float* e_fg = (const float*)d_in[33];  const float* e_fb = (const float*)d_in[34];

    const int XSZ  = NNODES * DMODEL;
    const int LGSZ = NEDGES * DMODEL;

    // ---- workspace layout ---------------------------------------------------
    char* ws = (char*)d_ws;
    unsigned short* lg16  = (unsigned short*)(ws);               // 51,200,000 B
    unsigned short* ve16  = (unsigned short*)(ws + 51200000);    // 51,200,000 B
    int* n_off = (int*)(ws + 102400000);
    int* n_cur = (int*)(ws + 102420480);
    int* n_idx = (int*)(ws + 102440960);
    int* e_off = (int*)(ws + 102641664);
    int* e_cur = (int*)(ws + 102842368);
    int* e_idx = (int*)(ws + 103043072);                         // ends 103.84 MB
    unsigned short* xbufA = (unsigned short*)(ws + 110400000);   // 5,120,000 B
    unsigned short* xbufB = (unsigned short*)(ws + 115520000);   // 5,120,000 B

    // ---- d_out scratch (112.64 MB) -----------------------------------------
    char* ob = (char*)d_out;
    unsigned short* qe16 = (unsigned short*)(ob);                // 51.2 MB
    unsigned short* ke16 = (unsigned short*)(ob + 51200000);     // 51.2 MB
    unsigned short* nq16 = (unsigned short*)(ob);
    unsigned short* nk16 = (unsigned short*)(ob + 5120000);
    unsigned short* nv16 = (unsigned short*)(ob + 10240000);
    unsigned short* nhid = (unsigned short*)(ob);                // 20.48 MB
    unsigned short* wtq  = (unsigned short*)(ob + 102400000);    // q|k|v contiguous
    unsigned short* wtk  = (unsigned short*)(ob + 102924288);
    unsigned short* wtv  = (unsigned short*)(ob + 103448576);
    unsigned short* wto  = (unsigned short*)(ob + 103972864);
    unsigned short* wtf1 = (unsigned short*)(ob + 104497152);    // 2 MB
    unsigned short* wtf2 = (unsigned short*)(ob + 106594304);    // 2 MB (ends 108.7 MB)

    // ---- init + CSR build ---------------------------------------------------
    cast_f2b_kernel<<<(XSZ + 255) / 256, 256, 0, stream>>>(x_in, xbufA, XSZ);
    gather_rel_kernel<<<(LGSZ + 255) / 256, 256, 0, stream>>>(rel_embed, edge_feat, lg16);

    zero(stream, n_cur, NNODES);
    zero(stream, e_cur, NEDGES);
    hist_kernel<<<(NEDGES + 255) / 256, 256, 0, stream>>>(dst_ids, n_cur, NEDGES);
    hist_kernel<<<(NELG + 255) / 256, 256, 0, stream>>>(lg_dst, e_cur, NELG);
    scan_kernel<<<1, 1024, 0, stream>>>(n_cur, n_off, n_cur, NNODES);
    scan_kernel<<<1, 1024, 0, stream>>>(e_cur, e_off, e_cur, NEDGES);
    scatter_kernel<<<(NEDGES + 255) / 256, 256, 0, stream>>>(dst_ids, n_cur, n_idx, NEDGES);
    scatter_kernel<<<(NELG + 255) / 256, 256, 0, stream>>>(lg_dst, e_cur, e_idx, NELG);

    unsigned short* xc = xbufA;
    unsigned short* xn = xbufB;

    for (int i = 0; i < NLAYERS; ++i) {
        const size_t wo  = (size_t)i * DMODEL * DMODEL;
        const size_t bo_ = (size_t)i * DMODEL;
        const size_t f1o = (size_t)i * DMODEL * 4 * DMODEL;
        const size_t b1o = (size_t)i * 4 * DMODEL;
        const size_t f2o = (size_t)i * 4 * DMODEL * DMODEL;

        // ================= node update (reads xc, lg16) =================
        tcast(stream, n_Wq + wo, wtq, 512, 512);
        tcast(stream, n_Wk + wo, wtk, 512, 512);
        tcast(stream, n_Wv + wo, wtv, 512, 512);
        tcast(stream, n_Wo + wo, wto, 512, 512);
        tcast(stream, n_f1 + f1o, wtf1, 512, 2048);
        tcast(stream, n_f2 + f2o, wtf2, 2048, 512);

        mgemm_qkv(stream, xc, wtq, n_bq + bo_,
                  nullptr, nullptr, nullptr, nullptr,
                  nq16, nk16, nv16, NNODES, 512);

        attend_kernel<<<NNODES, 256, 0, stream>>>(
            nq16, nk16, nv16, lg16, src_ids, n_off, n_idx, NNODES);

        mgemm(stream, nq16, wto, n_bo + bo_, xc, nullptr, xn, NNODES, 512, 512, 0);
        ln_kernel<<<(NNODES + 3) / 4, 256, 0, stream>>>(xn, n_lg + bo_, n_lb + bo_, NNODES);
        mgemm(stream, xn, wtf1, n_fb1 + b1o, nullptr, nullptr, nhid, NNODES, 512, 2048, 1);
        mgemm(stream, nhid, wtf2, n_fb2 + bo_, xn, nullptr, xn, NNODES, 2048, 512, 0);
        ln_kernel<<<(NNODES + 3) / 4, 256, 0, stream>>>(xn, n_fg + bo_, n_fb + bo_, NNODES);

        // ================= edge update (reads PRE-update xc) =================
        tcast(stream, e_Wq + wo, wtq, 512, 512);
        tcast(stream, e_Wk + wo, wtk, 512, 512);
        tcast(stream, e_Wv + wo, wtv, 512, 512);
        tcast(stream, e_Wo + wo, wto, 512, 512);

        mgemm_qkv(stream, lg16, wtq, e_bq + bo_,
                  xc, dst_ids, xc, src_ids,
                  qe16, ke16, ve16, NEDGES, 512);

        attend_kernel<<<NEDGES, 256, 0, stream>>>(
            qe16, ke16, ve16, nullptr, lg_src, e_off, e_idx, NEDGES);

        mgemm(stream, qe16, wto, e_bo + bo_, lg16, nullptr, lg16, NEDGES, 512, 512, 0);
        ln_kernel<<<(NEDGES + 3) / 4, 256, 0, stream>>>(lg16, e_lg + bo_, e_lb + bo_, NEDGES);

        tcast(stream, e_f1 + f1o, wtf1, 512, 2048);
        tcast(stream, e_f2 + f2o, wtf2, 2048, 512);
        for (int c = 0; c < 4; ++c) {
            unsigned short* y1c = lg16 + (size_t)c * 12500 * DMODEL;
            mgemm(stream, y1c, wtf1, e_fb1 + b1o, nullptr, nullptr, ve16, 12500, 512, 2048, 1);
            mgemm(stream, ve16, wtf2, e_fb2 + bo_, y1c, nullptr, y1c, 12500, 2048, 512, 0);
        }
        ln_kernel<<<(NEDGES + 3) / 4, 256, 0, stream>>>(lg16, e_fg + bo_, e_fb + bo_, NEDGES);

        unsigned short* t = xc; xc = xn; xn = t;
    }

    // final: bf16 -> fp32 d_out (all d_out scratch dead now)
    float* out_f = (float*)d_out;
    cast_b2f_kernel<<<(XSZ + 255) / 256, 256, 0, stream>>>(xc, out_f, XSZ);
    cast_b2f_kernel<<<(LGSZ + 255) / 256, 256, 0, stream>>>(lg16, out_f + XSZ, LGSZ);
}